// Round 7
// baseline (2529.488 us; speedup 1.0000x reference)
//
#include <hip/hip_runtime.h>
#include <hip/hip_bf16.h>
#include <stdint.h>
#include <stddef.h>

using bf16 = __hip_bfloat16;
typedef __attribute__((ext_vector_type(8))) short short8;
typedef __attribute__((ext_vector_type(4))) float f32x4;

constexpr int BATCH = 2048;
constexpr int NN    = 1024;
constexpr int H1C   = 3072;
constexpr int H2C   = 4096;
constexpr int CAP   = 128;   // max nnz per sparse row
constexpr int NPAN  = 4;     // batch panels (blockIdx.y = panel, SLOW dim -> temporal L2 window)
constexpr int PW    = 512;   // panel width (1 KB bf16 row-segment per wave)

// CSR global row offsets
constexpr int ROW_WV1 = 0;                 // 5*3072 rows, len 3072
constexpr int ROW_WO1 = 5 * H1C;           // 5*1024 rows, len 3072
constexpr int ROW_WV2 = ROW_WO1 + 5 * NN;  // 5*4096 rows, len 4096
constexpr int ROW_WO2 = ROW_WV2 + 5 * H2C; // 5*1024 rows, len 4096
constexpr int ROWS_TOTAL = ROW_WO2 + 5 * NN; // 46080

__device__ __forceinline__ unsigned short f2bf(float f) {
  unsigned u = __float_as_uint(f);
  unsigned r = 0x7FFFu + ((u >> 16) & 1u);
  return (unsigned short)((u + r) >> 16);
}
__device__ __forceinline__ float bf2f(short s) {
  return __uint_as_float(((unsigned)(unsigned short)s) << 16);
}

// phi-domain encode of a pre-activation x (where t = tanh(x/2)):
//   value = sign(x) * phi(|x|),  phi(y) = log((1+e^-y)/(1-e^-y)) = -log(tanh(y/2))
//   x == 0  ->  +inf  (encodes t==0, excluded from products)
__device__ __forceinline__ unsigned short phi_enc(float x) {
  const float e = expf(-fabsf(x));
  const float phi = logf((1.f + e) / (1.f - e));  // +inf iff x==0
  return (unsigned short)(f2bf(phi) | (unsigned short)((__float_as_uint(x) >> 31) << 15));
}

__device__ __forceinline__ void gload16(const void* g, void* lds_base) {
  __builtin_amdgcn_global_load_lds(
      (const __attribute__((address_space(1))) void*)g,
      (__attribute__((address_space(3))) void*)lds_base, 16, 0, 0);
}

// ---- bf16 MFMA GEMM (m97-structure): C[M,Nd] = A[M,K] @ BT[Nd,K]^T (+add), f32 and/or bf16 out
__global__ __launch_bounds__(256, 2) void gemm_bt(
    const bf16* __restrict__ A, const bf16* __restrict__ BT,
    float* __restrict__ C, bf16* __restrict__ Cb, const float* __restrict__ add,
    int M, int Nd, int K)
{
  __shared__ bf16 As[128 * 32];
  __shared__ bf16 Bs[128 * 32];
  const int tid  = threadIdx.x;
  const int lane = tid & 63;
  const int w    = tid >> 6;
  const int bn = blockIdx.x, bm = blockIdx.y;
  const int wm = (w >> 1) * 64, wn = (w & 1) * 64;
  const int l15 = lane & 15;
  const int lk  = (lane >> 4) * 8;
  const int ld4 = (lane >> 4) * 4;
  const int sr  = lane >> 2;
  const int kc  = (lane & 3) * 8;

  f32x4 acc[4][4];
#pragma unroll
  for (int i = 0; i < 4; ++i)
#pragma unroll
    for (int j = 0; j < 4; ++j)
#pragma unroll
      for (int e = 0; e < 4; ++e) acc[i][j][e] = 0.f;

  const size_t rA = (size_t)bm * 128;
  const size_t rB = (size_t)bn * 128;

  for (int kt = 0; kt < K; kt += 32) {
#pragma unroll
    for (int c = 0; c < 2; ++c) {
      const int slot = w * 2 + c;
      const int r = slot * 16 + sr;
      gload16(A  + (rA + r) * (size_t)K + kt + kc, &As[slot * 512]);
      gload16(BT + (rB + r) * (size_t)K + kt + kc, &Bs[slot * 512]);
    }
    __syncthreads();
    short8 af[4], bfr[4];
#pragma unroll
    for (int f = 0; f < 4; ++f) {
      af[f]  = *(const short8*)&As[(wm + f * 16 + l15) * 32 + lk];
      bfr[f] = *(const short8*)&Bs[(wn + f * 16 + l15) * 32 + lk];
    }
#pragma unroll
    for (int i = 0; i < 4; ++i)
#pragma unroll
      for (int j = 0; j < 4; ++j)
        acc[i][j] = __builtin_amdgcn_mfma_f32_16x16x32_bf16(af[i], bfr[j], acc[i][j], 0, 0, 0);
    __syncthreads();
  }

#pragma unroll
  for (int i = 0; i < 4; ++i) {
    const int row0 = bm * 128 + wm + i * 16 + ld4;
#pragma unroll
    for (int j = 0; j < 4; ++j) {
      const int col = bn * 128 + wn + j * 16 + l15;
#pragma unroll
      for (int e = 0; e < 4; ++e) {
        const size_t o = (size_t)(row0 + e) * Nd + col;
        float v = acc[i][j][e];
        if (add) v += add[o];
        if (C)  C[o] = v;
        if (Cb) Cb[o] = __float2bfloat16(v);
      }
    }
  }
}

// ---- prep: SmIT[k][n][m] = bf16(S[k][m][n] - (m==n))
__global__ __launch_bounds__(256) void prep_smit(const float* __restrict__ S, bf16* __restrict__ out)
{
  __shared__ float ls[64][65];
  const int k = blockIdx.z;
  const int n0 = blockIdx.x * 64, m0 = blockIdx.y * 64;
  const float* Sk = S + (size_t)k * NN * NN;
  bf16* ok = out + (size_t)k * NN * NN;
  const int tc = threadIdx.x & 63, tr = threadIdx.x >> 6;
#pragma unroll
  for (int i = 0; i < 16; ++i) {
    const int r = tr + i * 4;
    ls[r][tc] = Sk[(size_t)(m0 + r) * NN + n0 + tc];
  }
  __syncthreads();
#pragma unroll
  for (int i = 0; i < 16; ++i) {
    const int r = tr + i * 4;
    float v = ls[tc][r] - ((m0 + tc) == (n0 + r) ? 1.f : 0.f);
    ok[(size_t)(n0 + r) * NN + m0 + tc] = __float2bfloat16(v);
  }
}

// ---- prep: out[h][n] = bf16(Bsrc[n][h]);  Bsrc is (NN, H)
__global__ __launch_bounds__(256) void prep_bt(const float* __restrict__ Bsrc, bf16* __restrict__ out, int H)
{
  __shared__ float ls[64][65];
  const int h0 = blockIdx.x * 64, n0 = blockIdx.y * 64;
  const int tc = threadIdx.x & 63, tr = threadIdx.x >> 6;
#pragma unroll
  for (int i = 0; i < 16; ++i) {
    const int r = tr + i * 4;
    ls[r][tc] = Bsrc[(size_t)(n0 + r) * H + h0 + tc];
  }
  __syncthreads();
#pragma unroll
  for (int i = 0; i < 16; ++i) {
    const int r = tr + i * 4;
    out[(size_t)(h0 + r) * NN + n0 + tc] = __float2bfloat16(ls[tc][r]);
  }
}

// ---- CSR build: one block per row, ordered compaction (deterministic)
__global__ __launch_bounds__(256) void csr_build(
    const float* __restrict__ W, int rowlen,
    float* __restrict__ vals, int* __restrict__ cols, int* __restrict__ nnz, int row_off)
{
  const int row = blockIdx.x;
  const float* wr = W + (size_t)row * rowlen;
  const size_t base = (size_t)(row_off + row) * CAP;
  __shared__ int wtot[4];
  __shared__ int cbase;
  if (threadIdx.x == 0) cbase = 0;
  __syncthreads();
  const int lane = threadIdx.x & 63, wv = threadIdx.x >> 6;
  for (int c0 = 0; c0 < rowlen; c0 += 256) {
    const int c = c0 + threadIdx.x;
    const float v = wr[c];
    const bool nz = (v != 0.f);
    const unsigned long long m = __ballot(nz);
    const int rank = __popcll(m & ((1ull << lane) - 1ull));
    if (lane == 0) wtot[wv] = __popcll(m);
    __syncthreads();
    int pre = cbase;
    for (int i = 0; i < wv; ++i) pre += wtot[i];
    if (nz) {
      const int p = pre + rank;
      if (p < CAP) { vals[base + p] = v; cols[base + p] = c; }
    }
    __syncthreads();
    if (threadIdx.x == 0) cbase += wtot[0] + wtot[1] + wtot[2] + wtot[3];
    __syncthreads();
  }
  if (threadIdx.x == 0) nnz[row_off + row] = (cbase < CAP ? cbase : CAP);
}

// ---- cn_update + clip + 2*atanh, phi-domain source (bf16), panel-ordered:
//      wave w -> row h = bx*4+w; lanes cover panel by*512 + lane*8.
__global__ __launch_bounds__(256) void cn_kernel(
    const unsigned short* __restrict__ src,  // (rows, BATCH) bf16 phi-encoded
    const int* __restrict__ idx, int D,
    unsigned short* __restrict__ out)        // (H, BATCH) bf16 LLR
{
  const int w = threadIdx.x >> 6, lane = threadIdx.x & 63;
  const int h = blockIdx.x * 4 + w;
  const int b = blockIdx.y * PW + lane * 8;
  const int* ir = idx + (size_t)h * D;
  float s[8];
  unsigned sg[8];
  bool any[8];
#pragma unroll
  for (int e = 0; e < 8; ++e) { s[e] = 0.f; sg[e] = 0u; any[e] = false; }
  for (int d = 0; d < D; ++d) {
    const short8 v = *(const short8*)(src + (size_t)ir[d] * BATCH + b);
#pragma unroll
    for (int e = 0; e < 8; ++e) {
      const unsigned bits = (unsigned)(unsigned short)v[e];
      sg[e] ^= bits >> 15;
      const unsigned a = bits & 0x7FFFu;
      const bool nz = (a != 0x7F80u);   // +inf encodes t==0 (excluded)
      any[e] |= nz;
      s[e] += nz ? __uint_as_float(a << 16) : 0.f;
    }
  }
  short8 ov;
#pragma unroll
  for (int e = 0; e < 8; ++e) {
    const float y = fmaxf(s[e], 1.0000005e-6f);   // == clip(|u|, 0.999999)
    const float u = expf(-y);
    float r = logf((1.f + u) / (1.f - u));
    r = any[e] ? r : 0.f;
    ov[e] = (short)(f2bf(r) | (unsigned short)(sg[e] << 15));
  }
  *(short8*)(out + (size_t)h * BATCH + b) = ov;
}

// ---- sparse Wv apply, panel-ordered: t2p[h,b] = phi_enc( z[h,b] + sum val*t1[col,b] )
//      z is bf16 now (written by GEMM).
__global__ __launch_bounds__(256) void sparse_wv(
    const unsigned short* __restrict__ zb, const unsigned short* __restrict__ t1,
    const float* __restrict__ vals, const int* __restrict__ cols, const int* __restrict__ nnz,
    int rowoff, unsigned short* __restrict__ t2p)
{
  const int w = threadIdx.x >> 6, lane = threadIdx.x & 63;
  const int h = blockIdx.x * 4 + w;
  const int b = blockIdx.y * PW + lane * 8;
  const int rg = rowoff + h;
  const float* vr = vals + (size_t)rg * CAP;
  const int*   cr = cols + (size_t)rg * CAP;
  const int n = nnz[rg];
  const short8 z = *(const short8*)(zb + (size_t)h * BATCH + b);
  f32x4 a0, a1;
#pragma unroll
  for (int e = 0; e < 4; ++e) { a0[e] = bf2f(z[e]); a1[e] = bf2f(z[e + 4]); }
  for (int j = 0; j < n; ++j) {
    const float v = vr[j];
    const short8 t = *(const short8*)(t1 + (size_t)cr[j] * BATCH + b);
#pragma unroll
    for (int e = 0; e < 4; ++e) {
      a0[e] += v * bf2f(t[e]);
      a1[e] += v * bf2f(t[e + 4]);
    }
  }
  short8 ov;
#pragma unroll
  for (int e = 0; e < 4; ++e) {
    ov[e]     = (short)phi_enc(a0[e]);   // t2 = tanh(0.5*a) -> phi domain
    ov[e + 4] = (short)phi_enc(a1[e]);
  }
  *(short8*)(t2p + (size_t)h * BATCH + b) = ov;
}

// ---- sparse Wout apply, panel-ordered: xp[n,b] = sum val*t3[col,b]; t3 is bf16 LLR
__global__ __launch_bounds__(256) void sparse_wo(
    const unsigned short* __restrict__ t3,
    const float* __restrict__ vals, const int* __restrict__ cols, const int* __restrict__ nnz,
    int rowoff, float* __restrict__ xp)
{
  const int w = threadIdx.x >> 6, lane = threadIdx.x & 63;
  const int nrow = blockIdx.x * 4 + w;
  const int b = blockIdx.y * PW + lane * 8;
  const int rg = rowoff + nrow;
  const float* vr = vals + (size_t)rg * CAP;
  const int*   cr = cols + (size_t)rg * CAP;
  const int cnt = nnz[rg];
  f32x4 a0 = {0.f, 0.f, 0.f, 0.f};
  f32x4 a1 = {0.f, 0.f, 0.f, 0.f};
  for (int j = 0; j < cnt; ++j) {
    const float v = vr[j];
    const short8 t = *(const short8*)(t3 + (size_t)cr[j] * BATCH + b);
#pragma unroll
    for (int e = 0; e < 4; ++e) {
      a0[e] += v * bf2f(t[e]);
      a1[e] += v * bf2f(t[e + 4]);
    }
  }
  float* orow = xp + (size_t)nrow * BATCH + b;
  *(f32x4*)orow = a0;
  *(f32x4*)(orow + 4) = a1;
}

// ---- fused epilogue: x_new = chS + xp^T; sigmoid->out, x f32, x bf16 (B,N), phi(x)->tfT (N,B)
__global__ __launch_bounds__(256) void fuse_out(
    const float* __restrict__ xpT,
    const float* __restrict__ chS,
    float* __restrict__ dout,
    float* __restrict__ xf,
    bf16* __restrict__ xb,
    unsigned short* __restrict__ tfT)
{
  __shared__ float lc[64][65];
  __shared__ float lx[64][65];
  const int n0 = blockIdx.x * 64, b0 = blockIdx.y * 64;
  const int tc = threadIdx.x & 63, tr = threadIdx.x >> 6;
#pragma unroll
  for (int i = 0; i < 16; ++i) {
    const int r = tr + i * 4;
    lc[r][tc] = chS[(size_t)(b0 + r) * NN + n0 + tc];
    lx[r][tc] = xpT[(size_t)(n0 + r) * BATCH + b0 + tc];
  }
  __syncthreads();
#pragma unroll
  for (int i = 0; i < 16; ++i) {
    const int r = tr + i * 4;
    const float v = lc[r][tc] + lx[tc][r];
    const size_t o = (size_t)(b0 + r) * NN + n0 + tc;
    dout[o] = 1.f / (1.f + expf(-v));
    xf[o] = v;
    xb[o] = __float2bfloat16(v);
  }
#pragma unroll
  for (int i = 0; i < 16; ++i) {
    const int r = tr + i * 4;
    const float v = lc[tc][r] + lx[r][tc];
    tfT[(size_t)(n0 + r) * BATCH + b0 + tc] = phi_enc(v);
  }
}

// ---- initial prep (k=0): from x (B,N) make xb (B,N) and phi(x)->tfT (N,B)
__global__ __launch_bounds__(256) void init_prep(
    const float* __restrict__ x, bf16* __restrict__ xb, unsigned short* __restrict__ tfT)
{
  __shared__ float ls[64][65];
  const int n0 = blockIdx.x * 64, b0 = blockIdx.y * 64;
  const int tc = threadIdx.x & 63, tr = threadIdx.x >> 6;
#pragma unroll
  for (int i = 0; i < 16; ++i) {
    const int r = tr + i * 4;
    const size_t o = (size_t)(b0 + r) * NN + n0 + tc;
    const float v = x[o];
    ls[r][tc] = v;
    xb[o] = __float2bfloat16(v);
  }
  __syncthreads();
#pragma unroll
  for (int i = 0; i < 16; ++i) {
    const int r = tr + i * 4;
    tfT[(size_t)(n0 + r) * BATCH + b0 + tc] = phi_enc(ls[tc][r]);
  }
}

extern "C" void kernel_launch(void* const* d_in, const int* in_sizes, int n_in,
                              void* d_out, int out_size, void* d_ws, size_t ws_size,
                              hipStream_t stream)
{
  const float* x_in  = (const float*)d_in[0];
  const float* S     = (const float*)d_in[1];
  const float* B1    = (const float*)d_in[2];
  const float* B2    = (const float*)d_in[3];
  const float* Wv1   = (const float*)d_in[4];
  const float* Wout1 = (const float*)d_in[5];
  const float* Wv2   = (const float*)d_in[6];
  const float* Wout2 = (const float*)d_in[7];
  const int* idx1f   = (const int*)d_in[8];
  const int* idx1m   = (const int*)d_in[9];
  const int* idx2f   = (const int*)d_in[10];
  const int* idx2m   = (const int*)d_in[11];
  float* out = (float*)d_out;

  uint8_t* p = (uint8_t*)d_ws;
  auto alloc = [&](size_t bytes) -> void* {
    void* r = p;
    p += (bytes + 255) & ~(size_t)255;
    return r;
  };
  bf16*  SmIT = (bf16*)alloc((size_t)10 * NN * NN * sizeof(bf16));
  bf16*  B1T  = (bf16*)alloc((size_t)H1C * NN * sizeof(bf16));
  bf16*  B2T  = (bf16*)alloc((size_t)H2C * NN * sizeof(bf16));
  float* cvals = (float*)alloc((size_t)ROWS_TOTAL * CAP * sizeof(float));
  int*   ccols = (int*)alloc((size_t)ROWS_TOTAL * CAP * sizeof(int));
  int*   cnnz  = (int*)alloc((size_t)ROWS_TOTAL * sizeof(int));
  float* xf   = (float*)alloc((size_t)BATCH * NN * sizeof(float));
  bf16*  xb   = (bf16*)alloc((size_t)BATCH * NN * sizeof(bf16));
  unsigned short* tfT = (unsigned short*)alloc((size_t)NN * BATCH * sizeof(unsigned short)); // phi(x)
  float* chS  = (float*)alloc((size_t)BATCH * NN * sizeof(float));
  bf16*  chSb = (bf16*)alloc((size_t)BATCH * NN * sizeof(bf16));
  unsigned short* t1T = (unsigned short*)alloc((size_t)H2C * BATCH * sizeof(unsigned short)); // bf16 LLR t1/t3
  unsigned short* zTb = (unsigned short*)alloc((size_t)H2C * BATCH * sizeof(unsigned short)); // bf16 z
  unsigned short* t2p = (unsigned short*)alloc((size_t)H2C * BATCH * sizeof(unsigned short)); // phi(t2)
  float* xpT  = (float*)alloc((size_t)NN * BATCH * sizeof(float));
  (void)ws_size; (void)in_sizes; (void)n_in; (void)out_size;

  // --- per-call prep
  prep_smit<<<dim3(NN / 64, NN / 64, 10), 256, 0, stream>>>(S, SmIT);
  prep_bt<<<dim3(H1C / 64, NN / 64), 256, 0, stream>>>(B1, B1T, H1C);
  prep_bt<<<dim3(H2C / 64, NN / 64), 256, 0, stream>>>(B2, B2T, H2C);
  csr_build<<<5 * H1C, 256, 0, stream>>>(Wv1,   H1C, cvals, ccols, cnnz, ROW_WV1);
  csr_build<<<5 * NN,  256, 0, stream>>>(Wout1, H1C, cvals, ccols, cnnz, ROW_WO1);
  csr_build<<<5 * H2C, 256, 0, stream>>>(Wv2,   H2C, cvals, ccols, cnnz, ROW_WV2);
  csr_build<<<5 * NN,  256, 0, stream>>>(Wout2, H2C, cvals, ccols, cnnz, ROW_WO2);
  init_prep<<<dim3(NN / 64, BATCH / 64), 256, 0, stream>>>(x_in, xb, tfT);

  for (int k = 0; k < 10; ++k) {
    const bool g1 = (k % 2 == 0);
    const int j = k / 2;
    const int H = g1 ? H1C : H2C;
    const bf16* BmT = g1 ? B1T : B2T;
    const int* idf = g1 ? idx1f : idx2f;
    const int* idm = g1 ? idx1m : idx2m;
    const int D = g1 ? 6 : 8;
    const int wv_off = g1 ? (ROW_WV1 + j * H1C) : (ROW_WV2 + j * H2C);
    const int wo_off = g1 ? (ROW_WO1 + j * NN)  : (ROW_WO2 + j * NN);
    const float* xcur = (k == 0) ? x_in : xf;

    // chS = x + x @ (S[k]-I)
    gemm_bt<<<dim3(NN / 128, BATCH / 128), 256, 0, stream>>>(
        xb, SmIT + (size_t)k * NN * NN, chS, chSb, xcur, BATCH, NN, NN);
    // t1T = bf16 LLR of cn over phi-encoded tfT
    cn_kernel<<<dim3(H / 4, NPAN), 256, 0, stream>>>(tfT, idf, D, t1T);
    // zTb = bf16( BmT @ chS^T )
    gemm_bt<<<dim3(BATCH / 128, H / 128), 256, 0, stream>>>(
        BmT, chSb, nullptr, (bf16*)zTb, nullptr, H, BATCH, NN);
    // t2p = phi( z + Wv @ t1 )
    sparse_wv<<<dim3(H / 4, NPAN), 256, 0, stream>>>(zTb, t1T, cvals, ccols, cnnz, wv_off, t2p);
    // t3T = bf16 LLR of cn over phi-encoded t2p  -> t1T
    cn_kernel<<<dim3(H / 4, NPAN), 256, 0, stream>>>(t2p, idm, D, t1T);
    // xpT = Wout @ t3
    sparse_wo<<<dim3(NN / 4, NPAN), 256, 0, stream>>>(t1T, cvals, ccols, cnnz, wo_off, xpT);
    // epilogue
    fuse_out<<<dim3(NN / 64, BATCH / 64), 256, 0, stream>>>(
        xpT, chS, out + (size_t)k * BATCH * NN, xf, xb, tfT);
  }
}

// Round 8
// 2274.361 us; speedup vs baseline: 1.1122x; 1.1122x over previous
//
#include <hip/hip_runtime.h>
#include <hip/hip_bf16.h>
#include <stdint.h>
#include <stddef.h>

using bf16 = __hip_bfloat16;
typedef __attribute__((ext_vector_type(8))) short short8;
typedef __attribute__((ext_vector_type(4))) float f32x4;
typedef __attribute__((ext_vector_type(4))) unsigned u32x4;

constexpr int BATCH = 2048;
constexpr int NN    = 1024;
constexpr int H1C   = 3072;
constexpr int H2C   = 4096;
constexpr int CAP   = 128;   // max nnz per sparse row

// CSR global row offsets
constexpr int ROW_WV1 = 0;                 // 5*3072 rows, len 3072
constexpr int ROW_WO1 = 5 * H1C;           // 5*1024 rows, len 3072
constexpr int ROW_WV2 = ROW_WO1 + 5 * NN;  // 5*4096 rows, len 4096
constexpr int ROW_WO2 = ROW_WV2 + 5 * H2C; // 5*1024 rows, len 4096
constexpr int ROWS_TOTAL = ROW_WO2 + 5 * NN; // 46080

__device__ __forceinline__ unsigned short f2bf(float f) {
  unsigned u = __float_as_uint(f);
  unsigned r = 0x7FFFu + ((u >> 16) & 1u);
  return (unsigned short)((u + r) >> 16);
}
__device__ __forceinline__ float bf2f(short s) {
  return __uint_as_float(((unsigned)(unsigned short)s) << 16);
}

// phi-domain encode of a pre-activation x (where t = tanh(x/2)):
//   value = sign(x) * phi(|x|),  phi(y) = log((1+e^-y)/(1-e^-y)) = -log(tanh(y/2))
//   x == 0  ->  +inf  (encodes t==0, excluded from products)
__device__ __forceinline__ unsigned short phi_enc(float x) {
  const float e = expf(-fabsf(x));
  const float phi = logf((1.f + e) / (1.f - e));  // +inf iff x==0
  return (unsigned short)(f2bf(phi) | (unsigned short)((__float_as_uint(x) >> 31) << 15));
}

__device__ __forceinline__ void gload16(const void* g, void* lds_base) {
  __builtin_amdgcn_global_load_lds(
      (const __attribute__((address_space(1))) void*)g,
      (__attribute__((address_space(3))) void*)lds_base, 16, 0, 0);
}

// ---- bf16 MFMA GEMM (m97-structure): C[M,Nd] = A[M,K] @ BT[Nd,K]^T (+add), f32 and/or bf16 out
__global__ __launch_bounds__(256, 2) void gemm_bt(
    const bf16* __restrict__ A, const bf16* __restrict__ BT,
    float* __restrict__ C, bf16* __restrict__ Cb, const float* __restrict__ add,
    int M, int Nd, int K)
{
  __shared__ bf16 As[128 * 32];
  __shared__ bf16 Bs[128 * 32];
  const int tid  = threadIdx.x;
  const int lane = tid & 63;
  const int w    = tid >> 6;
  const int bn = blockIdx.x, bm = blockIdx.y;
  const int wm = (w >> 1) * 64, wn = (w & 1) * 64;
  const int l15 = lane & 15;
  const int lk  = (lane >> 4) * 8;
  const int ld4 = (lane >> 4) * 4;
  const int sr  = lane >> 2;
  const int kc  = (lane & 3) * 8;

  f32x4 acc[4][4];
#pragma unroll
  for (int i = 0; i < 4; ++i)
#pragma unroll
    for (int j = 0; j < 4; ++j)
#pragma unroll
      for (int e = 0; e < 4; ++e) acc[i][j][e] = 0.f;

  const size_t rA = (size_t)bm * 128;
  const size_t rB = (size_t)bn * 128;

  for (int kt = 0; kt < K; kt += 32) {
#pragma unroll
    for (int c = 0; c < 2; ++c) {
      const int slot = w * 2 + c;
      const int r = slot * 16 + sr;
      gload16(A  + (rA + r) * (size_t)K + kt + kc, &As[slot * 512]);
      gload16(BT + (rB + r) * (size_t)K + kt + kc, &Bs[slot * 512]);
    }
    __syncthreads();
    short8 af[4], bfr[4];
#pragma unroll
    for (int f = 0; f < 4; ++f) {
      af[f]  = *(const short8*)&As[(wm + f * 16 + l15) * 32 + lk];
      bfr[f] = *(const short8*)&Bs[(wn + f * 16 + l15) * 32 + lk];
    }
#pragma unroll
    for (int i = 0; i < 4; ++i)
#pragma unroll
      for (int j = 0; j < 4; ++j)
        acc[i][j] = __builtin_amdgcn_mfma_f32_16x16x32_bf16(af[i], bfr[j], acc[i][j], 0, 0, 0);
    __syncthreads();
  }

#pragma unroll
  for (int i = 0; i < 4; ++i) {
    const int row0 = bm * 128 + wm + i * 16 + ld4;
#pragma unroll
    for (int j = 0; j < 4; ++j) {
      const int col = bn * 128 + wn + j * 16 + l15;
#pragma unroll
      for (int e = 0; e < 4; ++e) {
        const size_t o = (size_t)(row0 + e) * Nd + col;
        float v = acc[i][j][e];
        if (add) v += add[o];
        if (C)  C[o] = v;
        if (Cb) Cb[o] = __float2bfloat16(v);
      }
    }
  }
}

// ---- prep: SmIT[k][n][m] = bf16(S[k][m][n] - (m==n))
__global__ __launch_bounds__(256) void prep_smit(const float* __restrict__ S, bf16* __restrict__ out)
{
  __shared__ float ls[64][65];
  const int k = blockIdx.z;
  const int n0 = blockIdx.x * 64, m0 = blockIdx.y * 64;
  const float* Sk = S + (size_t)k * NN * NN;
  bf16* ok = out + (size_t)k * NN * NN;
  const int tc = threadIdx.x & 63, tr = threadIdx.x >> 6;
#pragma unroll
  for (int i = 0; i < 16; ++i) {
    const int r = tr + i * 4;
    ls[r][tc] = Sk[(size_t)(m0 + r) * NN + n0 + tc];
  }
  __syncthreads();
#pragma unroll
  for (int i = 0; i < 16; ++i) {
    const int r = tr + i * 4;
    float v = ls[tc][r] - ((m0 + tc) == (n0 + r) ? 1.f : 0.f);
    ok[(size_t)(n0 + r) * NN + m0 + tc] = __float2bfloat16(v);
  }
}

// ---- prep: out[h][n] = bf16(Bsrc[n][h]);  Bsrc is (NN, H)
__global__ __launch_bounds__(256) void prep_bt(const float* __restrict__ Bsrc, bf16* __restrict__ out, int H)
{
  __shared__ float ls[64][65];
  const int h0 = blockIdx.x * 64, n0 = blockIdx.y * 64;
  const int tc = threadIdx.x & 63, tr = threadIdx.x >> 6;
#pragma unroll
  for (int i = 0; i < 16; ++i) {
    const int r = tr + i * 4;
    ls[r][tc] = Bsrc[(size_t)(n0 + r) * H + h0 + tc];
  }
  __syncthreads();
#pragma unroll
  for (int i = 0; i < 16; ++i) {
    const int r = tr + i * 4;
    out[(size_t)(h0 + r) * NN + n0 + tc] = __float2bfloat16(ls[tc][r]);
  }
}

// ---- CSR build: one block per row, ordered compaction (deterministic)
//      packed entry: u32 = bf16(val)<<16 | col
__global__ __launch_bounds__(256) void csr_build(
    const float* __restrict__ W, int rowlen,
    unsigned* __restrict__ pack, int* __restrict__ nnz, int row_off)
{
  const int row = blockIdx.x;
  const float* wr = W + (size_t)row * rowlen;
  const size_t base = (size_t)(row_off + row) * CAP;
  __shared__ int wtot[4];
  __shared__ int cbase;
  if (threadIdx.x == 0) cbase = 0;
  __syncthreads();
  const int lane = threadIdx.x & 63, wv = threadIdx.x >> 6;
  for (int c0 = 0; c0 < rowlen; c0 += 256) {
    const int c = c0 + threadIdx.x;
    const float v = wr[c];
    const bool nz = (v != 0.f);
    const unsigned long long m = __ballot(nz);
    const int rank = __popcll(m & ((1ull << lane) - 1ull));
    if (lane == 0) wtot[wv] = __popcll(m);
    __syncthreads();
    int pre = cbase;
    for (int i = 0; i < wv; ++i) pre += wtot[i];
    if (nz) {
      const int p = pre + rank;
      if (p < CAP) pack[base + p] = ((unsigned)f2bf(v) << 16) | (unsigned)c;
    }
    __syncthreads();
    if (threadIdx.x == 0) cbase += wtot[0] + wtot[1] + wtot[2] + wtot[3];
    __syncthreads();
  }
  if (threadIdx.x == 0) nnz[row_off + row] = (cbase < CAP ? cbase : CAP);
}

// ---- cn_update + clip + 2*atanh, phi-domain source (bf16), compile-time D (full unroll -> D gathers in flight)
template<int D>
__global__ __launch_bounds__(256) void cn_kernel(
    const unsigned short* __restrict__ src,  // (rows, BATCH) bf16 phi-encoded
    const int* __restrict__ idx,
    unsigned short* __restrict__ out)        // (H, BATCH) bf16 LLR
{
  const int h = blockIdx.x;
  const int b = threadIdx.x * 8;
  const int* ir = idx + (size_t)h * D;
  int rows[D];
#pragma unroll
  for (int d = 0; d < D; ++d) rows[d] = ir[d];
  short8 v[D];
#pragma unroll
  for (int d = 0; d < D; ++d)
    v[d] = *(const short8*)(src + (size_t)rows[d] * BATCH + b);
  float s[8];
  unsigned sg[8];
  bool any[8];
#pragma unroll
  for (int e = 0; e < 8; ++e) { s[e] = 0.f; sg[e] = 0u; any[e] = false; }
#pragma unroll
  for (int d = 0; d < D; ++d) {
#pragma unroll
    for (int e = 0; e < 8; ++e) {
      const unsigned bits = (unsigned)(unsigned short)v[d][e];
      sg[e] ^= bits >> 15;
      const unsigned a = bits & 0x7FFFu;
      const bool nz = (a != 0x7F80u);   // +inf encodes t==0 (excluded)
      any[e] |= nz;
      s[e] += nz ? __uint_as_float(a << 16) : 0.f;
    }
  }
  short8 ov;
#pragma unroll
  for (int e = 0; e < 8; ++e) {
    const float y = fmaxf(s[e], 1.0000005e-6f);   // == clip(|u|, 0.999999)
    const float u = expf(-y);
    float r = logf((1.f + u) / (1.f - u));
    r = any[e] ? r : 0.f;
    ov[e] = (short)(f2bf(r) | (unsigned short)(sg[e] << 15));
  }
  *(short8*)(out + (size_t)h * BATCH + b) = ov;
}

// ---- sparse Wv apply: t2p[h,b] = phi_enc( z[h,b] + sum val*t1[col,b] ), unroll-4 j-loop (4 gathers in flight)
__global__ __launch_bounds__(256) void sparse_wv(
    const unsigned short* __restrict__ zb, const unsigned short* __restrict__ t1,
    const unsigned* __restrict__ pack, const int* __restrict__ nnz,
    int rowoff, unsigned short* __restrict__ t2p)
{
  const int h = blockIdx.x;
  const int b = threadIdx.x * 8;
  const int rg = rowoff + h;
  const unsigned* pr = pack + (size_t)rg * CAP;
  const int n = nnz[rg];
  const short8 z = *(const short8*)(zb + (size_t)h * BATCH + b);
  f32x4 a0, a1;
#pragma unroll
  for (int e = 0; e < 4; ++e) { a0[e] = bf2f(z[e]); a1[e] = bf2f(z[e + 4]); }
  int j = 0;
  for (; j + 4 <= n; j += 4) {
    const u32x4 w4 = *(const u32x4*)(pr + j);
    short8 t[4];
#pragma unroll
    for (int q = 0; q < 4; ++q)
      t[q] = *(const short8*)(t1 + (size_t)(w4[q] & 0xFFFFu) * BATCH + b);
#pragma unroll
    for (int q = 0; q < 4; ++q) {
      const float v = bf2f((short)(w4[q] >> 16));
#pragma unroll
      for (int e = 0; e < 4; ++e) {
        a0[e] += v * bf2f(t[q][e]);
        a1[e] += v * bf2f(t[q][e + 4]);
      }
    }
  }
  for (; j < n; ++j) {
    const unsigned pk = pr[j];
    const float v = bf2f((short)(pk >> 16));
    const short8 t = *(const short8*)(t1 + (size_t)(pk & 0xFFFFu) * BATCH + b);
#pragma unroll
    for (int e = 0; e < 4; ++e) {
      a0[e] += v * bf2f(t[e]);
      a1[e] += v * bf2f(t[e + 4]);
    }
  }
  short8 ov;
#pragma unroll
  for (int e = 0; e < 4; ++e) {
    ov[e]     = (short)phi_enc(a0[e]);   // t2 = tanh(0.5*a) -> phi domain
    ov[e + 4] = (short)phi_enc(a1[e]);
  }
  *(short8*)(t2p + (size_t)h * BATCH + b) = ov;
}

// ---- sparse Wout apply: xp[n,b] = sum val*t3[col,b], unroll-4 j-loop
__global__ __launch_bounds__(256) void sparse_wo(
    const unsigned short* __restrict__ t3,
    const unsigned* __restrict__ pack, const int* __restrict__ nnz,
    int rowoff, float* __restrict__ xp)
{
  const int nrow = blockIdx.x;
  const int b = threadIdx.x * 8;
  const int rg = rowoff + nrow;
  const unsigned* pr = pack + (size_t)rg * CAP;
  const int cnt = nnz[rg];
  f32x4 a0 = {0.f, 0.f, 0.f, 0.f};
  f32x4 a1 = {0.f, 0.f, 0.f, 0.f};
  int j = 0;
  for (; j + 4 <= cnt; j += 4) {
    const u32x4 w4 = *(const u32x4*)(pr + j);
    short8 t[4];
#pragma unroll
    for (int q = 0; q < 4; ++q)
      t[q] = *(const short8*)(t3 + (size_t)(w4[q] & 0xFFFFu) * BATCH + b);
#pragma unroll
    for (int q = 0; q < 4; ++q) {
      const float v = bf2f((short)(w4[q] >> 16));
#pragma unroll
      for (int e = 0; e < 4; ++e) {
        a0[e] += v * bf2f(t[q][e]);
        a1[e] += v * bf2f(t[q][e + 4]);
      }
    }
  }
  for (; j < cnt; ++j) {
    const unsigned pk = pr[j];
    const float v = bf2f((short)(pk >> 16));
    const short8 t = *(const short8*)(t3 + (size_t)(pk & 0xFFFFu) * BATCH + b);
#pragma unroll
    for (int e = 0; e < 4; ++e) {
      a0[e] += v * bf2f(t[e]);
      a1[e] += v * bf2f(t[e + 4]);
    }
  }
  float* orow = xp + (size_t)nrow * BATCH + b;
  *(f32x4*)orow = a0;
  *(f32x4*)(orow + 4) = a1;
}

// ---- fused epilogue: x_new = chS + xp^T; sigmoid->out, x f32, x bf16 (B,N), phi(x)->tfT (N,B)
__global__ __launch_bounds__(256) void fuse_out(
    const float* __restrict__ xpT,
    const float* __restrict__ chS,
    float* __restrict__ dout,
    float* __restrict__ xf,
    bf16* __restrict__ xb,
    unsigned short* __restrict__ tfT)
{
  __shared__ float lc[64][65];
  __shared__ float lx[64][65];
  const int n0 = blockIdx.x * 64, b0 = blockIdx.y * 64;
  const int tc = threadIdx.x & 63, tr = threadIdx.x >> 6;
#pragma unroll
  for (int i = 0; i < 16; ++i) {
    const int r = tr + i * 4;
    lc[r][tc] = chS[(size_t)(b0 + r) * NN + n0 + tc];
    lx[r][tc] = xpT[(size_t)(n0 + r) * BATCH + b0 + tc];
  }
  __syncthreads();
#pragma unroll
  for (int i = 0; i < 16; ++i) {
    const int r = tr + i * 4;
    const float v = lc[r][tc] + lx[tc][r];
    const size_t o = (size_t)(b0 + r) * NN + n0 + tc;
    dout[o] = 1.f / (1.f + expf(-v));
    xf[o] = v;
    xb[o] = __float2bfloat16(v);
  }
#pragma unroll
  for (int i = 0; i < 16; ++i) {
    const int r = tr + i * 4;
    const float v = lc[tc][r] + lx[r][tc];
    tfT[(size_t)(n0 + r) * BATCH + b0 + tc] = phi_enc(v);
  }
}

// ---- initial prep (k=0): from x (B,N) make xb (B,N) and phi(x)->tfT (N,B)
__global__ __launch_bounds__(256) void init_prep(
    const float* __restrict__ x, bf16* __restrict__ xb, unsigned short* __restrict__ tfT)
{
  __shared__ float ls[64][65];
  const int n0 = blockIdx.x * 64, b0 = blockIdx.y * 64;
  const int tc = threadIdx.x & 63, tr = threadIdx.x >> 6;
#pragma unroll
  for (int i = 0; i < 16; ++i) {
    const int r = tr + i * 4;
    const size_t o = (size_t)(b0 + r) * NN + n0 + tc;
    const float v = x[o];
    ls[r][tc] = v;
    xb[o] = __float2bfloat16(v);
  }
  __syncthreads();
#pragma unroll
  for (int i = 0; i < 16; ++i) {
    const int r = tr + i * 4;
    tfT[(size_t)(n0 + r) * BATCH + b0 + tc] = phi_enc(ls[tc][r]);
  }
}

extern "C" void kernel_launch(void* const* d_in, const int* in_sizes, int n_in,
                              void* d_out, int out_size, void* d_ws, size_t ws_size,
                              hipStream_t stream)
{
  const float* x_in  = (const float*)d_in[0];
  const float* S     = (const float*)d_in[1];
  const float* B1    = (const float*)d_in[2];
  const float* B2    = (const float*)d_in[3];
  const float* Wv1   = (const float*)d_in[4];
  const float* Wout1 = (const float*)d_in[5];
  const float* Wv2   = (const float*)d_in[6];
  const float* Wout2 = (const float*)d_in[7];
  const int* idx1f   = (const int*)d_in[8];
  const int* idx1m   = (const int*)d_in[9];
  const int* idx2f   = (const int*)d_in[10];
  const int* idx2m   = (const int*)d_in[11];
  float* out = (float*)d_out;

  uint8_t* p = (uint8_t*)d_ws;
  auto alloc = [&](size_t bytes) -> void* {
    void* r = p;
    p += (bytes + 255) & ~(size_t)255;
    return r;
  };
  bf16*  SmIT = (bf16*)alloc((size_t)10 * NN * NN * sizeof(bf16));
  bf16*  B1T  = (bf16*)alloc((size_t)H1C * NN * sizeof(bf16));
  bf16*  B2T  = (bf16*)alloc((size_t)H2C * NN * sizeof(bf16));
  unsigned* cpack = (unsigned*)alloc((size_t)ROWS_TOTAL * CAP * sizeof(unsigned));
  int*   cnnz  = (int*)alloc((size_t)ROWS_TOTAL * sizeof(int));
  float* xf   = (float*)alloc((size_t)BATCH * NN * sizeof(float));
  bf16*  xb   = (bf16*)alloc((size_t)BATCH * NN * sizeof(bf16));
  unsigned short* tfT = (unsigned short*)alloc((size_t)NN * BATCH * sizeof(unsigned short)); // phi(x)
  float* chS  = (float*)alloc((size_t)BATCH * NN * sizeof(float));
  bf16*  chSb = (bf16*)alloc((size_t)BATCH * NN * sizeof(bf16));
  unsigned short* t1T = (unsigned short*)alloc((size_t)H2C * BATCH * sizeof(unsigned short)); // bf16 LLR t1/t3
  unsigned short* zTb = (unsigned short*)alloc((size_t)H2C * BATCH * sizeof(unsigned short)); // bf16 z
  unsigned short* t2p = (unsigned short*)alloc((size_t)H2C * BATCH * sizeof(unsigned short)); // phi(t2)
  float* xpT  = (float*)alloc((size_t)NN * BATCH * sizeof(float));
  (void)ws_size; (void)in_sizes; (void)n_in; (void)out_size;

  // --- per-call prep
  prep_smit<<<dim3(NN / 64, NN / 64, 10), 256, 0, stream>>>(S, SmIT);
  prep_bt<<<dim3(H1C / 64, NN / 64), 256, 0, stream>>>(B1, B1T, H1C);
  prep_bt<<<dim3(H2C / 64, NN / 64), 256, 0, stream>>>(B2, B2T, H2C);
  csr_build<<<5 * H1C, 256, 0, stream>>>(Wv1,   H1C, cpack, cnnz, ROW_WV1);
  csr_build<<<5 * NN,  256, 0, stream>>>(Wout1, H1C, cpack, cnnz, ROW_WO1);
  csr_build<<<5 * H2C, 256, 0, stream>>>(Wv2,   H2C, cpack, cnnz, ROW_WV2);
  csr_build<<<5 * NN,  256, 0, stream>>>(Wout2, H2C, cpack, cnnz, ROW_WO2);
  init_prep<<<dim3(NN / 64, BATCH / 64), 256, 0, stream>>>(x_in, xb, tfT);

  for (int k = 0; k < 10; ++k) {
    const bool g1 = (k % 2 == 0);
    const int j = k / 2;
    const int H = g1 ? H1C : H2C;
    const bf16* BmT = g1 ? B1T : B2T;
    const int* idf = g1 ? idx1f : idx2f;
    const int* idm = g1 ? idx1m : idx2m;
    const int wv_off = g1 ? (ROW_WV1 + j * H1C) : (ROW_WV2 + j * H2C);
    const int wo_off = g1 ? (ROW_WO1 + j * NN)  : (ROW_WO2 + j * NN);
    const float* xcur = (k == 0) ? x_in : xf;

    // chS = x + x @ (S[k]-I)
    gemm_bt<<<dim3(NN / 128, BATCH / 128), 256, 0, stream>>>(
        xb, SmIT + (size_t)k * NN * NN, chS, chSb, xcur, BATCH, NN, NN);
    // t1T = bf16 LLR of cn over phi-encoded tfT
    if (g1) cn_kernel<6><<<dim3(H, 1), 256, 0, stream>>>(tfT, idf, t1T);
    else    cn_kernel<8><<<dim3(H, 1), 256, 0, stream>>>(tfT, idf, t1T);
    // zTb = bf16( BmT @ chS^T )
    gemm_bt<<<dim3(BATCH / 128, H / 128), 256, 0, stream>>>(
        BmT, chSb, nullptr, (bf16*)zTb, nullptr, H, BATCH, NN);
    // t2p = phi( z + Wv @ t1 )
    sparse_wv<<<dim3(H, 1), 256, 0, stream>>>(zTb, t1T, cpack, cnnz, wv_off, t2p);
    // t3T = bf16 LLR of cn over phi-encoded t2p  -> t1T
    if (g1) cn_kernel<6><<<dim3(H, 1), 256, 0, stream>>>(t2p, idm, t1T);
    else    cn_kernel<8><<<dim3(H, 1), 256, 0, stream>>>(t2p, idm, t1T);
    // xpT = Wout @ t3
    sparse_wo<<<dim3(NN, 1), 256, 0, stream>>>(t1T, cpack, cnnz, wo_off, xpT);
    // epilogue
    fuse_out<<<dim3(NN / 64, BATCH / 64), 256, 0, stream>>>(
        xpT, chS, out + (size_t)k * BATCH * NN, xf, xb, tfT);
  }
}